// Round 4
// baseline (1382.475 us; speedup 1.0000x reference)
//
#include <hip/hip_runtime.h>
#include <math.h>

#define V_SIZE 50257
#define EMB 512
#define HID 512
#define NB 32
#define TT 128
#define NSTEP 127
#define G3H 1536
#define MROWS 4064   // NSTEP*NB
#define MPAD 4096
#define VPAD 50304   // 393*128
#define NT_V 393
#define NBLK_GRU 32
#define NTILE_E 6288  // 16 m-chunks x 393 n-tiles
#define GRU_SMEM 77312

typedef __attribute__((ext_vector_type(4))) float f32x4;
typedef __attribute__((ext_vector_type(8))) __bf16 bf16x8;
typedef __attribute__((ext_vector_type(4))) __bf16 bf16x4;

struct u128 { unsigned long long a, b; };

// async global->LDS, 16B per lane; LDS dst is wave-uniform base + lane*16
__device__ __forceinline__ void async16(const __bf16* g, __bf16* l) {
    __builtin_amdgcn_global_load_lds(
        (const __attribute__((address_space(1))) void*)g,
        (__attribute__((address_space(3))) void*)l, 16, 0, 0);
}

// ---------------- merged prep kernel ----------------
#define PREP_EMIT_BLKS 4096
#define PREP_WIH_BLKS 768
#define PREP_X_BLKS 128
#define PREP_GRID (PREP_EMIT_BLKS + PREP_WIH_BLKS + PREP_X_BLKS + NB + 1)

__global__ __launch_bounds__(256) void k_prep(
    const int* __restrict__ words, const float* __restrict__ embed,
    const float* __restrict__ emit_W, const float* __restrict__ W_ih,
    const float* __restrict__ h0,
    __bf16* __restrict__ emit_Wb, __bf16* __restrict__ Wihb,
    __bf16* __restrict__ Xb, __bf16* __restrict__ Hs,
    __bf16* __restrict__ Hbuf, int* __restrict__ ctrl)
{
    int b = blockIdx.x;
    int tid = threadIdx.x;
    if (b < PREP_EMIT_BLKS) {
        size_t total4 = (size_t)VPAD * 512 / 4;
        size_t real4  = (size_t)V_SIZE * 512 / 4;
        for (size_t i4 = (size_t)b * 256 + tid; i4 < total4;
             i4 += (size_t)PREP_EMIT_BLKS * 256) {
            float4 v = (i4 < real4) ? ((const float4*)emit_W)[i4] : make_float4(0.f,0.f,0.f,0.f);
            bf16x4 o = {(__bf16)v.x, (__bf16)v.y, (__bf16)v.z, (__bf16)v.w};
            ((bf16x4*)emit_Wb)[i4] = o;
        }
    } else if (b < PREP_EMIT_BLKS + PREP_WIH_BLKS) {
        size_t i4 = (size_t)(b - PREP_EMIT_BLKS) * 256 + tid;  // exactly covers G3H*512/4
        float4 v = ((const float4*)W_ih)[i4];
        bf16x4 o = {(__bf16)v.x, (__bf16)v.y, (__bf16)v.z, (__bf16)v.w};
        ((bf16x4*)Wihb)[i4] = o;
    } else if (b < PREP_EMIT_BLKS + PREP_WIH_BLKS + PREP_X_BLKS) {
        int s = b - (PREP_EMIT_BLKS + PREP_WIH_BLKS);   // 0..127
        if (s < NSTEP) {
            for (int idx = tid; idx < 32 * 128; idx += 256) {
                int n = idx >> 7, c = idx & 127;
                int w = words[n * TT + s];
                float4 v = ((const float4*)(embed + (size_t)w * EMB))[c];
                bf16x4 o = {(__bf16)v.x, (__bf16)v.y, (__bf16)v.z, (__bf16)v.w};
                ((bf16x4*)(Xb + (size_t)(s * NB + n) * EMB))[c] = o;
            }
        } else {
            bf16x4 z = {(__bf16)0.f, (__bf16)0.f, (__bf16)0.f, (__bf16)0.f};
            for (int idx = tid; idx < 32 * 128; idx += 256) {
                int n = idx >> 7, c = idx & 127;
                ((bf16x4*)(Xb + (size_t)(MROWS + n) * EMB))[c] = z;
                ((bf16x4*)(Hs + (size_t)(MROWS + n) * HID))[c] = z;
            }
        }
    } else {
        int b2 = b - (PREP_EMIT_BLKS + PREP_WIH_BLKS + PREP_X_BLKS);
        if (b2 < NB) {
            for (int k = tid; k < HID; k += 256)
                Hbuf[b2 * HID + k] = (__bf16)h0[b2 * HID + k];
        } else {
            for (int k = tid; k < 2048; k += 256) ctrl[k] = 0;
        }
    }
}

// ---------------- 128x128 MFMA mainloop (gi GEMM) ----------------
__device__ __forceinline__ void mm128(const __bf16* __restrict__ A,
                                      const __bf16* __restrict__ B,
                                      int mBase, int nBase, f32x4 acc[4][4],
                                      __bf16* As, __bf16* Bs) {
    const int tid = threadIdx.x;
    const int lane = tid & 63, wave = tid >> 6;
    const int wm = wave >> 1, wn = wave & 1;
    const int lane15 = lane & 15, quad = lane >> 4;
    for (int kc = 0; kc < 512; kc += 64) {
        __syncthreads();
#pragma unroll
        for (int i = 0; i < 4; ++i) {
            int c = (wave * 4 + i) * 64 + lane;   // 16B chunk id, 0..1023
            int row = c >> 3, ci = c & 7;
            int cis = ci ^ (row & 7);
            async16(A + (size_t)(mBase + row) * 512 + kc + (cis << 3), As + (wave * 4 + i) * 512);
            async16(B + (size_t)(nBase + row) * 512 + kc + (cis << 3), Bs + (wave * 4 + i) * 512);
        }
        __syncthreads();
#pragma unroll
        for (int ks = 0; ks < 64; ks += 32) {
            bf16x8 a4[4], b4[4];
#pragma unroll
            for (int mi = 0; mi < 4; ++mi) {
                int row = wm * 64 + mi * 16 + lane15;
                int L = (ks >> 3) + quad;
                a4[mi] = *(const bf16x8*)(As + row * 64 + ((L ^ (row & 7)) << 3));
            }
#pragma unroll
            for (int ni = 0; ni < 4; ++ni) {
                int row = wn * 64 + ni * 16 + lane15;
                int L = (ks >> 3) + quad;
                b4[ni] = *(const bf16x8*)(Bs + row * 64 + ((L ^ (row & 7)) << 3));
            }
#pragma unroll
            for (int mi = 0; mi < 4; ++mi)
#pragma unroll
                for (int ni = 0; ni < 4; ++ni)
                    acc[mi][ni] = __builtin_amdgcn_mfma_f32_16x16x32_bf16(
                        a4[mi], b4[ni], acc[mi][ni], 0, 0, 0);
        }
    }
}

// gi = Xb @ W_ih^T + b_ih (+ b_hh for r,z gates)  -> fp32 [MPAD][1536]
__global__ __launch_bounds__(256) void k_gemm_gi(const __bf16* __restrict__ Xb,
                                                 const __bf16* __restrict__ Wihb,
                                                 const float* __restrict__ b_ih,
                                                 const float* __restrict__ b_hh,
                                                 float* __restrict__ gi) {
    __shared__ __align__(16) __bf16 As[128 * 64];
    __shared__ __align__(16) __bf16 Bs[128 * 64];
    f32x4 acc[4][4];
    f32x4 z = {0.f, 0.f, 0.f, 0.f};
#pragma unroll
    for (int mi = 0; mi < 4; ++mi)
#pragma unroll
        for (int ni = 0; ni < 4; ++ni) acc[mi][ni] = z;
    int mBase = blockIdx.x * 128, nBase = blockIdx.y * 128;
    mm128(Xb, Wihb, mBase, nBase, acc, As, Bs);
    const int tid = threadIdx.x, lane = tid & 63, wave = tid >> 6;
    const int wm = wave >> 1, wn = wave & 1, lane15 = lane & 15, quad = lane >> 4;
#pragma unroll
    for (int ni = 0; ni < 4; ++ni) {
        int col = nBase + wn * 64 + ni * 16 + lane15;
        float bias = b_ih[col] + (col < 1024 ? b_hh[col] : 0.0f);
#pragma unroll
        for (int mi = 0; mi < 4; ++mi) {
            int rowb = wm * 64 + mi * 16 + quad * 4;
#pragma unroll
            for (int r = 0; r < 4; ++r) {
                int m = mBase + rowb + r;
                gi[(size_t)m * G3H + col] = acc[mi][ni][r] + bias;
            }
        }
    }
}

// ---------------- GRU-only kernel (32 blocks, quiet machine) ----------------
// block blk owns h cols [blk*16,+16); per-step cross-block barrier via one
// packed 128B flag line (wave-0 coalesced poll).
#define CREDp(w,g,m,jc) Cred[(((w)*3+(g))*32+(m))*17+(jc)]

__global__ __launch_bounds__(256, 2) void k_gru(
    const float* __restrict__ W_hh, const float* __restrict__ gi,
    const float* __restrict__ b_hh, const float* __restrict__ h0,
    __bf16* __restrict__ Hbuf,   // [2][32][512] bf16 ping-pong
    __bf16* __restrict__ Hs,     // [MPAD][512] bf16
    float* __restrict__ Hfin,    // [32][512] fp32
    int* __restrict__ ctrl)      // [0..31] = packed step flags (one line)
{
    __shared__ __align__(16) char smem[GRU_SMEM];
    const int tid = threadIdx.x;
    const int lane = tid & 63, wave = tid >> 6;
    const int lane15 = lane & 15, quad = lane >> 4;
    int* flags = ctrl;

    const int blk = blockIdx.x;
    const int j0 = blk * 16;
    __bf16* Wl  = (__bf16*)smem;                    // 48*520*2 = 49920
    float* Cred = (float*)(smem + 49920);           // 4*3*32*17*4 = 26112
    __bf16 (*HbO)[16] = (__bf16(*)[16])(smem + 76032); // 1024

    for (int idx = tid; idx < 48 * 128; idx += 256) {
        int rr = idx >> 7, k4 = (idx & 127) << 2;
        int g = rr >> 4, jc = rr & 15;
        float4 v = *(const float4*)(W_hh + (size_t)(g * 512 + j0 + jc) * 512 + k4);
        __bf16* d = &Wl[rr * 520 + k4];
        d[0] = (__bf16)v.x; d[1] = (__bf16)v.y; d[2] = (__bf16)v.z; d[3] = (__bf16)v.w;
    }

    const int m0 = tid >> 4, jc0 = tid & 15;
    const int m1 = m0 + 16;
    const float bhn = b_hh[1024 + j0 + jc0];
    const int k0 = wave * 128;
    float hp0 = h0[(size_t)m0 * HID + j0 + jc0];
    float hp1 = h0[(size_t)m1 * HID + j0 + jc0];

    float ir0, iz0, in0, ir1, iz1, in1;
    {
        const float* g0 = gi + (size_t)m0 * G3H + j0 + jc0;
        const float* g1 = gi + (size_t)m1 * G3H + j0 + jc0;
        ir0 = g0[0]; iz0 = g0[512]; in0 = g0[1024];
        ir1 = g1[0]; iz1 = g1[512]; in1 = g1[1024];
    }
    __syncthreads();

    for (int s = 0; s < NSTEP; ++s) {
        const __bf16* hb = Hbuf + (size_t)(s & 1) * NB * HID;
        unsigned long long hq[2][4][2];
#pragma unroll
        for (int mt = 0; mt < 2; ++mt)
#pragma unroll
            for (int kk = 0; kk < 4; ++kk) {
                const unsigned long long* pp = (const unsigned long long*)
                    (hb + (size_t)(mt * 16 + lane15) * HID + k0 + kk * 32 + quad * 8);
                hq[mt][kk][0] = __hip_atomic_load(pp, __ATOMIC_RELAXED, __HIP_MEMORY_SCOPE_AGENT);
                hq[mt][kk][1] = __hip_atomic_load(pp + 1, __ATOMIC_RELAXED, __HIP_MEMORY_SCOPE_AGENT);
            }

        f32x4 acc[2][3];
        f32x4 zz = {0.f, 0.f, 0.f, 0.f};
#pragma unroll
        for (int mt = 0; mt < 2; ++mt)
#pragma unroll
            for (int g = 0; g < 3; ++g) acc[mt][g] = zz;
#pragma unroll
        for (int kk = 0; kk < 4; ++kk) {
            int ks = kk * 32;
            bf16x8 a0 = __builtin_bit_cast(bf16x8, u128{hq[0][kk][0], hq[0][kk][1]});
            bf16x8 a1 = __builtin_bit_cast(bf16x8, u128{hq[1][kk][0], hq[1][kk][1]});
#pragma unroll
            for (int g = 0; g < 3; ++g) {
                bf16x8 b4 = *(const bf16x8*)(&Wl[(g * 16 + lane15) * 520 + k0 + ks + quad * 8]);
                acc[0][g] = __builtin_amdgcn_mfma_f32_16x16x32_bf16(a0, b4, acc[0][g], 0, 0, 0);
                acc[1][g] = __builtin_amdgcn_mfma_f32_16x16x32_bf16(a1, b4, acc[1][g], 0, 0, 0);
            }
        }
#pragma unroll
        for (int mt = 0; mt < 2; ++mt)
#pragma unroll
            for (int g = 0; g < 3; ++g)
#pragma unroll
                for (int r = 0; r < 4; ++r)
                    CREDp(wave, g, mt * 16 + quad * 4 + r, lane15) = acc[mt][g][r];
        __syncthreads();

        {
            float gr = CREDp(0,0,m0,jc0) + CREDp(1,0,m0,jc0) + CREDp(2,0,m0,jc0) + CREDp(3,0,m0,jc0);
            float gz = CREDp(0,1,m0,jc0) + CREDp(1,1,m0,jc0) + CREDp(2,1,m0,jc0) + CREDp(3,1,m0,jc0);
            float gn = CREDp(0,2,m0,jc0) + CREDp(1,2,m0,jc0) + CREDp(2,2,m0,jc0) + CREDp(3,2,m0,jc0);
            float r = 1.f / (1.f + expf(-(ir0 + gr)));
            float zg = 1.f / (1.f + expf(-(iz0 + gz)));
            float nn = tanhf(in0 + r * (gn + bhn));
            hp0 = (1.f - zg) * nn + zg * hp0;
            HbO[m0][jc0] = (__bf16)hp0;
        }
        {
            float gr = CREDp(0,0,m1,jc0) + CREDp(1,0,m1,jc0) + CREDp(2,0,m1,jc0) + CREDp(3,0,m1,jc0);
            float gz = CREDp(0,1,m1,jc0) + CREDp(1,1,m1,jc0) + CREDp(2,1,m1,jc0) + CREDp(3,1,m1,jc0);
            float gn = CREDp(0,2,m1,jc0) + CREDp(1,2,m1,jc0) + CREDp(2,2,m1,jc0) + CREDp(3,2,m1,jc0);
            float r = 1.f / (1.f + expf(-(ir1 + gr)));
            float zg = 1.f / (1.f + expf(-(iz1 + gz)));
            float nn = tanhf(in1 + r * (gn + bhn));
            hp1 = (1.f - zg) * nn + zg * hp1;
            HbO[m1][jc0] = (__bf16)hp1;
        }
        __syncthreads();

        // publish own 16-col slice (Hbuf ping-pong + Hs)
        if (tid < 128) {
            int m = tid >> 2, g4 = tid & 3;
            unsigned long long v0 = *(const unsigned short*)&HbO[m][g4 * 4 + 0];
            unsigned long long v1 = *(const unsigned short*)&HbO[m][g4 * 4 + 1];
            unsigned long long v2 = *(const unsigned short*)&HbO[m][g4 * 4 + 2];
            unsigned long long v3 = *(const unsigned short*)&HbO[m][g4 * 4 + 3];
            unsigned long long pk = v0 | (v1 << 16) | (v2 << 32) | (v3 << 48);
            unsigned long long* dst = (unsigned long long*)
                (Hbuf + (size_t)((s + 1) & 1) * NB * HID + (size_t)m * HID + j0 + g4 * 4);
            __hip_atomic_store(dst, pk, __ATOMIC_RELAXED, __HIP_MEMORY_SCOPE_AGENT);
            unsigned long long* dst2 = (unsigned long long*)
                (Hs + (size_t)(s * NB + m) * HID + j0 + g4 * 4);
            __hip_atomic_store(dst2, pk, __ATOMIC_RELAXED, __HIP_MEMORY_SCOPE_AGENT);
        }

        // drain publish stores only (gi prefetch not yet issued)
        __builtin_amdgcn_s_waitcnt(0x0f70);
        __syncthreads();

        if (tid == 0)
            __hip_atomic_store(&flags[blk], s + 1,
                               __ATOMIC_RELAXED, __HIP_MEMORY_SCOPE_AGENT);

        // prefetch next step's gi (hidden behind the poll)
        float nir0, niz0, nin0, nir1, niz1, nin1;
        if (s + 1 < NSTEP) {
            const float* g0 = gi + (size_t)((s + 1) * NB + m0) * G3H + j0 + jc0;
            const float* g1 = gi + (size_t)((s + 1) * NB + m1) * G3H + j0 + jc0;
            nir0 = g0[0]; niz0 = g0[512]; nin0 = g0[1024];
            nir1 = g1[0]; niz1 = g1[512]; nin1 = g1[1024];
        } else {
            nir0 = niz0 = nin0 = nir1 = niz1 = nin1 = 0.f;
        }

        // wave-0 coalesced poll of the single packed flag line
        if (wave == 0) {
            for (;;) {
                int f = __hip_atomic_load(&flags[lane & 31], __ATOMIC_RELAXED,
                                          __HIP_MEMORY_SCOPE_AGENT);
                if (__all(f >= s + 1)) break;
                __builtin_amdgcn_s_sleep(1);
            }
        }
        __syncthreads();

        ir0 = nir0; iz0 = niz0; in0 = nin0;
        ir1 = nir1; iz1 = niz1; in1 = nin1;
    }

    Hfin[(size_t)m0 * HID + j0 + jc0] = hp0;
    Hfin[(size_t)m1 * HID + j0 + jc0] = hp1;
}

// ---------------- standalone emit GEMM + row-chunk softmax partials ----------------
// 6288 blocks, 48KB LDS -> 3 blocks/CU. Bijective XCD swizzle: block orig runs
// on XCD orig%8; give XCD k the n-major swz range [k*786,(k+1)*786) so each
// XCD sweeps ~49 n-tiles x all 16 m-chunks: B slice ~6.4MB streams once, A
// (Hs, 4MB) stays L2-resident.
__global__ __launch_bounds__(256, 3) void k_emit(
    const __bf16* __restrict__ Hs, const __bf16* __restrict__ Wemb,
    const float* __restrict__ emit_b, float2* __restrict__ partials)
{
    __shared__ __align__(16) __bf16 As[256 * 64];   // 32768 B
    __shared__ __align__(16) __bf16 Bs[128 * 64];   // 16384 B
    const int tid = threadIdx.x;
    const int lane = tid & 63, wave = tid >> 6;
    const int lane15 = lane & 15, quad = lane >> 4;
    const float NINF = -__builtin_inff();

    int orig = blockIdx.x;                      // 0..6287
    int swz  = (orig & 7) * 786 + (orig >> 3);  // 6288 = 8*786, bijective
    int nT = swz >> 4, mc = swz & 15;           // n-major within XCD chunk
    int mBase = mc * 256, nBase = nT * 128;

    f32x4 acc[4][8];
    f32x4 z = {0.f, 0.f, 0.f, 0.f};
#pragma unroll
    for (int mi = 0; mi < 4; ++mi)
#pragma unroll
        for (int ni = 0; ni < 8; ++ni) acc[mi][ni] = z;

    for (int kc = 0; kc < 512; kc += 64) {
        __syncthreads();
#pragma unroll
        for (int i = 0; i < 8; ++i) {
            int c = (wave * 8 + i) * 64 + lane;   // 0..2047
            int row = c >> 3, ci = c & 7;
            int cis = ci ^ (row & 7);
            async16(Hs + (size_t)(mBase + row) * 512 + kc + (cis << 3),
                    As + (wave * 8 + i) * 512);
        }
#pragma unroll
        for (int i = 0; i < 4; ++i) {
            int c = (wave * 4 + i) * 64 + lane;   // 0..1023
            int row = c >> 3, ci = c & 7;
            int cis = ci ^ (row & 7);
            async16(Wemb + (size_t)(nBase + row) * 512 + kc + (cis << 3),
                    Bs + (wave * 4 + i) * 512);
        }
        __syncthreads();
#pragma unroll
        for (int ks = 0; ks < 64; ks += 32) {
            int L = (ks >> 3) + quad;
            bf16x8 a4[4], b4[8];
#pragma unroll
            for (int mi = 0; mi < 4; ++mi) {
                int row = wave * 64 + mi * 16 + lane15;
                a4[mi] = *(const bf16x8*)(As + row * 64 + ((L ^ (row & 7)) << 3));
            }
#pragma unroll
            for (int ni = 0; ni < 8; ++ni) {
                int row = ni * 16 + lane15;
                b4[ni] = *(const bf16x8*)(Bs + row * 64 + ((L ^ (row & 7)) << 3));
            }
#pragma unroll
            for (int mi = 0; mi < 4; ++mi)
#pragma unroll
                for (int ni = 0; ni < 8; ++ni)
                    acc[mi][ni] = __builtin_amdgcn_mfma_f32_16x16x32_bf16(
                        a4[mi], b4[ni], acc[mi][ni], 0, 0, 0);
        }
    }

    float bv[8];
    bool valid[8];
#pragma unroll
    for (int ni = 0; ni < 8; ++ni) {
        int col = nBase + ni * 16 + lane15;
        valid[ni] = (col < V_SIZE);
        bv[ni] = valid[ni] ? emit_b[col] : 0.0f;
    }
#pragma unroll
    for (int mi = 0; mi < 4; ++mi) {
#pragma unroll
        for (int r = 0; r < 4; ++r) {
            float vals[8];
            float vmax = NINF;
#pragma unroll
            for (int ni = 0; ni < 8; ++ni) {
                float v = acc[mi][ni][r] + bv[ni];
                if (!valid[ni]) v = NINF;
                vals[ni] = v;
                vmax = fmaxf(vmax, v);
            }
#pragma unroll
            for (int off = 1; off < 16; off <<= 1)
                vmax = fmaxf(vmax, __shfl_xor(vmax, off));
            float ssum = 0.f;
#pragma unroll
            for (int ni = 0; ni < 8; ++ni) ssum += expf(vals[ni] - vmax);
#pragma unroll
            for (int off = 1; off < 16; off <<= 1) ssum += __shfl_xor(ssum, off);
            if (lane15 == 0) {
                int m = mBase + wave * 64 + mi * 16 + quad * 4 + r;
                partials[(size_t)m * NT_V + nT] = make_float2(vmax, ssum);
            }
        }
    }
}

// ---------------- per-row log-likelihood ----------------
__global__ __launch_bounds__(128) void k_row_ll(const float2* __restrict__ partials,
                                                const __bf16* __restrict__ Hs,
                                                const __bf16* __restrict__ Wemb,
                                                const float* __restrict__ emit_b,
                                                const int* __restrict__ words,
                                                float* __restrict__ lls) {
    int s = blockIdx.x, n = blockIdx.y;
    int m = s * NB + n;
    int tid = threadIdx.x;
    int lane = tid & 63, w = tid >> 6;
    __shared__ float sm[2], ss[2], sd[2];
    const float2* prow = partials + (size_t)m * NT_V;
    float M = -__builtin_inff();
    for (int i = tid; i < NT_V; i += 128) M = fmaxf(M, prow[i].x);
#pragma unroll
    for (int off = 1; off < 64; off <<= 1) M = fmaxf(M, __shfl_xor(M, off));
    if (lane == 0) sm[w] = M;
    __syncthreads();
    M = fmaxf(sm[0], sm[1]);
    float S = 0.f;
    for (int i = tid; i < NT_V; i += 128) {
        float2 p = prow[i];
        S += p.y * expf(p.x - M);
    }
#pragma unroll
    for (int off = 1; off < 64; off <<= 1) S += __shfl_xor(S, off);
    if (lane == 0) ss[w] = S;
    __syncthreads();
    S = ss[0] + ss[1];
    int tw = words[n * TT + s + 1];
    float d = 0.f;
    const __bf16* hr = Hs + (size_t)m * HID;
    const __bf16* wr = Wemb + (size_t)tw * HID;
    for (int k = tid; k < HID; k += 128) d += (float)hr[k] * (float)wr[k];
#pragma unroll
    for (int off = 1; off < 64; off <<= 1) d += __shfl_xor(d, off);
    if (lane == 0) sd[w] = d;
    __syncthreads();
    if (tid == 0) {
        float dt = sd[0] + sd[1];
        lls[m] = dt + emit_b[tw] - (M + logf(S));
    }
}

// ---------------- final reduce ----------------
__global__ __launch_bounds__(128) void k_final(const float* __restrict__ lls,
                                               const float* __restrict__ Hfin,
                                               float* __restrict__ out) {
    int n = blockIdx.x;
    int tid = threadIdx.x;
    float s = 0.f;
    for (int i = tid; i < NSTEP; i += 128) s += lls[i * NB + n];
#pragma unroll
    for (int off = 1; off < 64; off <<= 1) s += __shfl_xor(s, off);
    __shared__ float t2[2];
    if ((tid & 63) == 0) t2[tid >> 6] = s;
    __syncthreads();
    if (tid == 0) out[n] = (t2[0] + t2[1]) / (float)NSTEP;
    for (int i = tid; i < HID; i += 128) out[NB + n * HID + i] = Hfin[(size_t)n * HID + i];
}

// ---------------- launch ----------------
extern "C" void kernel_launch(void* const* d_in, const int* in_sizes, int n_in,
                              void* d_out, int out_size, void* d_ws, size_t ws_size,
                              hipStream_t stream) {
    const int*   words   = (const int*)d_in[0];
    const float* hidden0 = (const float*)d_in[1];
    const float* embed_W = (const float*)d_in[2];
    const float* W_ih    = (const float*)d_in[3];
    const float* W_hh    = (const float*)d_in[4];
    const float* b_ih    = (const float*)d_in[5];
    const float* b_hh    = (const float*)d_in[6];
    const float* emit_W  = (const float*)d_in[7];
    const float* emit_b  = (const float*)d_in[8];
    float* out = (float*)d_out;

    char* p = (char*)d_ws;
    auto alloc = [&](size_t bytes) {
        void* r = (void*)p;
        p += (bytes + 255) & ~(size_t)255;
        return r;
    };
    __bf16* emit_Wb = (__bf16*)alloc((size_t)VPAD * 512 * 2);
    __bf16* Xb      = (__bf16*)alloc((size_t)MPAD * 512 * 2);
    __bf16* Wihb    = (__bf16*)alloc((size_t)G3H * 512 * 2);
    float*  gi      = (float*)alloc((size_t)MPAD * G3H * 4);
    __bf16* Hs      = (__bf16*)alloc((size_t)MPAD * 512 * 2);
    __bf16* Hbuf    = (__bf16*)alloc((size_t)2 * NB * HID * 2);
    float*  Hfin    = (float*)alloc((size_t)NB * HID * 4);
    float2* partials= (float2*)alloc((size_t)MPAD * NT_V * 8);
    float*  lls     = (float*)alloc((size_t)MROWS * 4);
    int*    ctrl    = (int*)alloc(2048 * 4);

    k_prep<<<PREP_GRID, 256, 0, stream>>>(words, embed_W, emit_W, W_ih, hidden0,
                                          emit_Wb, Wihb, Xb, Hs, Hbuf, ctrl);

    k_gemm_gi<<<dim3(32, 12), 256, 0, stream>>>(Xb, Wihb, b_ih, b_hh, gi);

    k_gru<<<NBLK_GRU, 256, 0, stream>>>(W_hh, gi, b_hh, hidden0, Hbuf, Hs, Hfin, ctrl);

    k_emit<<<NTILE_E, 256, 0, stream>>>(Hs, emit_Wb, emit_b, partials);

    k_row_ll<<<dim3(NSTEP, 32), 128, 0, stream>>>(partials, Hs, emit_Wb, emit_b, words, lls);
    k_final<<<32, 128, 0, stream>>>(lls, Hfin, out);
}

// Round 6
// 897.096 us; speedup vs baseline: 1.5411x; 1.5411x over previous
//
#include <hip/hip_runtime.h>
#include <math.h>

#define V_SIZE 50257
#define EMB 512
#define HID 512
#define NB 32
#define TT 128
#define NSTEP 127
#define G3H 1536
#define MROWS 4064   // NSTEP*NB
#define MPAD 4096
#define VPAD 50304   // 393*128
#define NT_V 393
#define NBLK_GRU 32
#define NTILE (16 * NT_V) // 16 m-chunks of 256 rows x 393 col-tiles
#define NWORKER 224       // 1 block/CU (98KB LDS); 32+224=256 blocks, all resident
#define SMEM_BYTES 98304

typedef __attribute__((ext_vector_type(4))) float f32x4;
typedef __attribute__((ext_vector_type(8))) __bf16 bf16x8;
typedef __attribute__((ext_vector_type(4))) __bf16 bf16x4;

struct u128 { unsigned long long a, b; };

// async global->LDS, 16B per lane; LDS dst is wave-uniform base + lane*16
__device__ __forceinline__ void async16(const __bf16* g, __bf16* l) {
    __builtin_amdgcn_global_load_lds(
        (const __attribute__((address_space(1))) void*)g,
        (__attribute__((address_space(3))) void*)l, 16, 0, 0);
}

// ---------------- merged prep kernel ----------------
#define PREP_EMIT_BLKS 4096
#define PREP_WIH_BLKS 768
#define PREP_X_BLKS 128
#define PREP_GRID (PREP_EMIT_BLKS + PREP_WIH_BLKS + PREP_X_BLKS + NB + 1)

__global__ __launch_bounds__(256) void k_prep(
    const int* __restrict__ words, const float* __restrict__ embed,
    const float* __restrict__ emit_W, const float* __restrict__ W_ih,
    const float* __restrict__ h0,
    __bf16* __restrict__ emit_Wb, __bf16* __restrict__ Wihb,
    __bf16* __restrict__ Xb, __bf16* __restrict__ Hs,
    __bf16* __restrict__ Hbuf, int* __restrict__ ctrl)
{
    int b = blockIdx.x;
    int tid = threadIdx.x;
    if (b < PREP_EMIT_BLKS) {
        size_t total4 = (size_t)VPAD * 512 / 4;
        size_t real4  = (size_t)V_SIZE * 512 / 4;
        for (size_t i4 = (size_t)b * 256 + tid; i4 < total4;
             i4 += (size_t)PREP_EMIT_BLKS * 256) {
            float4 v = (i4 < real4) ? ((const float4*)emit_W)[i4] : make_float4(0.f,0.f,0.f,0.f);
            bf16x4 o = {(__bf16)v.x, (__bf16)v.y, (__bf16)v.z, (__bf16)v.w};
            ((bf16x4*)emit_Wb)[i4] = o;
        }
    } else if (b < PREP_EMIT_BLKS + PREP_WIH_BLKS) {
        size_t i4 = (size_t)(b - PREP_EMIT_BLKS) * 256 + tid;  // exactly covers G3H*512/4
        float4 v = ((const float4*)W_ih)[i4];
        bf16x4 o = {(__bf16)v.x, (__bf16)v.y, (__bf16)v.z, (__bf16)v.w};
        ((bf16x4*)Wihb)[i4] = o;
    } else if (b < PREP_EMIT_BLKS + PREP_WIH_BLKS + PREP_X_BLKS) {
        int s = b - (PREP_EMIT_BLKS + PREP_WIH_BLKS);   // 0..127
        if (s < NSTEP) {
            for (int idx = tid; idx < 32 * 128; idx += 256) {
                int n = idx >> 7, c = idx & 127;
                int w = words[n * TT + s];
                float4 v = ((const float4*)(embed + (size_t)w * EMB))[c];
                bf16x4 o = {(__bf16)v.x, (__bf16)v.y, (__bf16)v.z, (__bf16)v.w};
                ((bf16x4*)(Xb + (size_t)(s * NB + n) * EMB))[c] = o;
            }
        } else {
            bf16x4 z = {(__bf16)0.f, (__bf16)0.f, (__bf16)0.f, (__bf16)0.f};
            for (int idx = tid; idx < 32 * 128; idx += 256) {
                int n = idx >> 7, c = idx & 127;
                ((bf16x4*)(Xb + (size_t)(MROWS + n) * EMB))[c] = z;
                ((bf16x4*)(Hs + (size_t)(MROWS + n) * HID))[c] = z;
            }
        }
    } else {
        int b2 = b - (PREP_EMIT_BLKS + PREP_WIH_BLKS + PREP_X_BLKS);
        if (b2 < NB) {
            for (int k = tid; k < HID; k += 256)
                Hbuf[b2 * HID + k] = (__bf16)h0[b2 * HID + k];
        } else {
            for (int k = tid; k < 2048; k += 256) ctrl[k] = 0;
        }
    }
}

// ---------------- 128x128 MFMA mainloop (gi GEMM) ----------------
__device__ __forceinline__ void mm128(const __bf16* __restrict__ A,
                                      const __bf16* __restrict__ B,
                                      int mBase, int nBase, f32x4 acc[4][4],
                                      __bf16* As, __bf16* Bs) {
    const int tid = threadIdx.x;
    const int lane = tid & 63, wave = tid >> 6;
    const int wm = wave >> 1, wn = wave & 1;
    const int lane15 = lane & 15, quad = lane >> 4;
    for (int kc = 0; kc < 512; kc += 64) {
        __syncthreads();
#pragma unroll
        for (int i = 0; i < 4; ++i) {
            int c = (wave * 4 + i) * 64 + lane;   // 16B chunk id, 0..1023
            int row = c >> 3, ci = c & 7;
            int cis = ci ^ (row & 7);
            async16(A + (size_t)(mBase + row) * 512 + kc + (cis << 3), As + (wave * 4 + i) * 512);
            async16(B + (size_t)(nBase + row) * 512 + kc + (cis << 3), Bs + (wave * 4 + i) * 512);
        }
        __syncthreads();
#pragma unroll
        for (int ks = 0; ks < 64; ks += 32) {
            bf16x8 a4[4], b4[4];
#pragma unroll
            for (int mi = 0; mi < 4; ++mi) {
                int row = wm * 64 + mi * 16 + lane15;
                int L = (ks >> 3) + quad;
                a4[mi] = *(const bf16x8*)(As + row * 64 + ((L ^ (row & 7)) << 3));
            }
#pragma unroll
            for (int ni = 0; ni < 4; ++ni) {
                int row = wn * 64 + ni * 16 + lane15;
                int L = (ks >> 3) + quad;
                b4[ni] = *(const bf16x8*)(Bs + row * 64 + ((L ^ (row & 7)) << 3));
            }
#pragma unroll
            for (int mi = 0; mi < 4; ++mi)
#pragma unroll
                for (int ni = 0; ni < 4; ++ni)
                    acc[mi][ni] = __builtin_amdgcn_mfma_f32_16x16x32_bf16(
                        a4[mi], b4[ni], acc[mi][ni], 0, 0, 0);
        }
    }
}

// gi = Xb @ W_ih^T + b_ih (+ b_hh for r,z gates)  -> fp32 [MPAD][1536]
__global__ __launch_bounds__(256) void k_gemm_gi(const __bf16* __restrict__ Xb,
                                                 const __bf16* __restrict__ Wihb,
                                                 const float* __restrict__ b_ih,
                                                 const float* __restrict__ b_hh,
                                                 float* __restrict__ gi) {
    __shared__ __align__(16) __bf16 As[128 * 64];
    __shared__ __align__(16) __bf16 Bs[128 * 64];
    f32x4 acc[4][4];
    f32x4 z = {0.f, 0.f, 0.f, 0.f};
#pragma unroll
    for (int mi = 0; mi < 4; ++mi)
#pragma unroll
        for (int ni = 0; ni < 4; ++ni) acc[mi][ni] = z;
    int mBase = blockIdx.x * 128, nBase = blockIdx.y * 128;
    mm128(Xb, Wihb, mBase, nBase, acc, As, Bs);
    const int tid = threadIdx.x, lane = tid & 63, wave = tid >> 6;
    const int wm = wave >> 1, wn = wave & 1, lane15 = lane & 15, quad = lane >> 4;
#pragma unroll
    for (int ni = 0; ni < 4; ++ni) {
        int col = nBase + wn * 64 + ni * 16 + lane15;
        float bias = b_ih[col] + (col < 1024 ? b_hh[col] : 0.0f);
#pragma unroll
        for (int mi = 0; mi < 4; ++mi) {
            int rowb = wm * 64 + mi * 16 + quad * 4;
#pragma unroll
            for (int r = 0; r < 4; ++r) {
                int m = mBase + rowb + r;
                gi[(size_t)m * G3H + col] = acc[mi][ni][r] + bias;
            }
        }
    }
}

// ---------------- fused persistent kernel: GRU producers + emit workers ----------------
// blocks 0..31: GRU (block blk owns h cols [blk*16,+16)) — unchanged from the
//   874µs baseline (packed flag line, 8 progress replicas).
// blocks 32..255: persistent emit workers, DOUBLE-BUFFERED LDS with counted
//   vmcnt (T3/T4-lite): stage kc+1 into the other buffer, s_waitcnt vmcnt(12)
//   (never 0 mid-loop), raw s_barrier (no drain), compute kc. 98KB LDS ->
//   1 block/CU; grid = 256 = CU count, all blocks resident (no deadlock).
// ctrl layout (ints): [0]=ticket | [32..63]=packed flags (one line)
//                     | [64 + i*32]=progress replica i (i=0..7)
#define CREDp(w,g,m,jc) Cred[(((w)*3+(g))*32+(m))*17+(jc)]

__global__ __launch_bounds__(256, 1) void k_fused(
    const float* __restrict__ W_hh, const float* __restrict__ gi,
    const float* __restrict__ b_hh, const float* __restrict__ h0,
    __bf16* __restrict__ Hbuf,   // [2][32][512] bf16 ping-pong
    __bf16* __restrict__ Hs,     // [MPAD][512] bf16
    float* __restrict__ Hfin,    // [32][512] fp32
    const __bf16* __restrict__ Wemb,
    const float* __restrict__ emit_b,
    float2* __restrict__ partials,
    int* __restrict__ ctrl)
{
    __shared__ __align__(16) char smem[SMEM_BYTES];
    __shared__ int tShare;
    const int tid = threadIdx.x;
    const int lane = tid & 63, wave = tid >> 6;
    const int lane15 = lane & 15, quad = lane >> 4;
    int* ticket = ctrl;
    int* flags  = ctrl + 32;          // 32 ints, ONE 128-B line
    int* prog   = ctrl + 64;          // 8 replicas, stride 32 ints

    if (blockIdx.x < NBLK_GRU) {
        // ================= GRU producer (unchanged) =================
        const int blk = blockIdx.x;
        const int j0 = blk * 16;
        __bf16* Wl  = (__bf16*)smem;                    // 48*520*2 = 49920
        float* Cred = (float*)(smem + 49920);           // 4*3*32*17*4 = 26112
        __bf16 (*HbO)[16] = (__bf16(*)[16])(smem + 76032); // 1024

        for (int idx = tid; idx < 48 * 128; idx += 256) {
            int rr = idx >> 7, k4 = (idx & 127) << 2;
            int g = rr >> 4, jc = rr & 15;
            float4 v = *(const float4*)(W_hh + (size_t)(g * 512 + j0 + jc) * 512 + k4);
            __bf16* d = &Wl[rr * 520 + k4];
            d[0] = (__bf16)v.x; d[1] = (__bf16)v.y; d[2] = (__bf16)v.z; d[3] = (__bf16)v.w;
        }

        const int m0 = tid >> 4, jc0 = tid & 15;
        const int m1 = m0 + 16;
        const float bhn = b_hh[1024 + j0 + jc0];
        const int k0 = wave * 128;
        float hp0 = h0[(size_t)m0 * HID + j0 + jc0];
        float hp1 = h0[(size_t)m1 * HID + j0 + jc0];

        float ir0, iz0, in0, ir1, iz1, in1;
        {
            const float* g0 = gi + (size_t)m0 * G3H + j0 + jc0;
            const float* g1 = gi + (size_t)m1 * G3H + j0 + jc0;
            ir0 = g0[0]; iz0 = g0[512]; in0 = g0[1024];
            ir1 = g1[0]; iz1 = g1[512]; in1 = g1[1024];
        }
        __syncthreads();

        for (int s = 0; s < NSTEP; ++s) {
            const __bf16* hb = Hbuf + (size_t)(s & 1) * NB * HID;
            unsigned long long hq[2][4][2];
#pragma unroll
            for (int mt = 0; mt < 2; ++mt)
#pragma unroll
                for (int kk = 0; kk < 4; ++kk) {
                    const unsigned long long* pp = (const unsigned long long*)
                        (hb + (size_t)(mt * 16 + lane15) * HID + k0 + kk * 32 + quad * 8);
                    hq[mt][kk][0] = __hip_atomic_load(pp, __ATOMIC_RELAXED, __HIP_MEMORY_SCOPE_AGENT);
                    hq[mt][kk][1] = __hip_atomic_load(pp + 1, __ATOMIC_RELAXED, __HIP_MEMORY_SCOPE_AGENT);
                }

            f32x4 acc[2][3];
            f32x4 zz = {0.f, 0.f, 0.f, 0.f};
#pragma unroll
            for (int mt = 0; mt < 2; ++mt)
#pragma unroll
                for (int g = 0; g < 3; ++g) acc[mt][g] = zz;
#pragma unroll
            for (int kk = 0; kk < 4; ++kk) {
                int ks = kk * 32;
                bf16x8 a0 = __builtin_bit_cast(bf16x8, u128{hq[0][kk][0], hq[0][kk][1]});
                bf16x8 a1 = __builtin_bit_cast(bf16x8, u128{hq[1][kk][0], hq[1][kk][1]});
#pragma unroll
                for (int g = 0; g < 3; ++g) {
                    bf16x8 b4 = *(const bf16x8*)(&Wl[(g * 16 + lane15) * 520 + k0 + ks + quad * 8]);
                    acc[0][g] = __builtin_amdgcn_mfma_f32_16x16x32_bf16(a0, b4, acc[0][g], 0, 0, 0);
                    acc[1][g] = __builtin_amdgcn_mfma_f32_16x16x32_bf16(a1, b4, acc[1][g], 0, 0, 0);
                }
            }
#pragma unroll
            for (int mt = 0; mt < 2; ++mt)
#pragma unroll
                for (int g = 0; g < 3; ++g)
#pragma unroll
                    for (int r = 0; r < 4; ++r)
                        CREDp(wave, g, mt * 16 + quad * 4 + r, lane15) = acc[mt][g][r];
            __syncthreads();

            {
                float gr = CREDp(0,0,m0,jc0) + CREDp(1,0,m0,jc0) + CREDp(2,0,m0,jc0) + CREDp(3,0,m0,jc0);
                float gz = CREDp(0,1,m0,jc0) + CREDp(1,1,m0,jc0) + CREDp(2,1,m0,jc0) + CREDp(3,1,m0,jc0);
                float gn = CREDp(0,2,m0,jc0) + CREDp(1,2,m0,jc0) + CREDp(2,2,m0,jc0) + CREDp(3,2,m0,jc0);
                float r = 1.f / (1.f + expf(-(ir0 + gr)));
                float zg = 1.f / (1.f + expf(-(iz0 + gz)));
                float nn = tanhf(in0 + r * (gn + bhn));
                hp0 = (1.f - zg) * nn + zg * hp0;
                HbO[m0][jc0] = (__bf16)hp0;
            }
            {
                float gr = CREDp(0,0,m1,jc0) + CREDp(1,0,m1,jc0) + CREDp(2,0,m1,jc0) + CREDp(3,0,m1,jc0);
                float gz = CREDp(0,1,m1,jc0) + CREDp(1,1,m1,jc0) + CREDp(2,1,m1,jc0) + CREDp(3,1,m1,jc0);
                float gn = CREDp(0,2,m1,jc0) + CREDp(1,2,m1,jc0) + CREDp(2,2,m1,jc0) + CREDp(3,2,m1,jc0);
                float r = 1.f / (1.f + expf(-(ir1 + gr)));
                float zg = 1.f / (1.f + expf(-(iz1 + gz)));
                float nn = tanhf(in1 + r * (gn + bhn));
                hp1 = (1.f - zg) * nn + zg * hp1;
                HbO[m1][jc0] = (__bf16)hp1;
            }
            __syncthreads();

            // publish own 16-col slice (Hbuf ping-pong + Hs)
            if (tid < 128) {
                int m = tid >> 2, g4 = tid & 3;
                unsigned long long v0 = *(const unsigned short*)&HbO[m][g4 * 4 + 0];
                unsigned long long v1 = *(const unsigned short*)&HbO[m][g4 * 4 + 1];
                unsigned long long v2 = *(const unsigned short*)&HbO[m][g4 * 4 + 2];
                unsigned long long v3 = *(const unsigned short*)&HbO[m][g4 * 4 + 3];
                unsigned long long pk = v0 | (v1 << 16) | (v2 << 32) | (v3 << 48);
                unsigned long long* dst = (unsigned long long*)
                    (Hbuf + (size_t)((s + 1) & 1) * NB * HID + (size_t)m * HID + j0 + g4 * 4);
                __hip_atomic_store(dst, pk, __ATOMIC_RELAXED, __HIP_MEMORY_SCOPE_AGENT);
                unsigned long long* dst2 = (unsigned long long*)
                    (Hs + (size_t)(s * NB + m) * HID + j0 + g4 * 4);
                __hip_atomic_store(dst2, pk, __ATOMIC_RELAXED, __HIP_MEMORY_SCOPE_AGENT);
            }

            // drain publish stores only (gi prefetch not yet issued)
            __builtin_amdgcn_s_waitcnt(0x0f70);
            __syncthreads();

            if (tid == 0)
                __hip_atomic_store(&flags[blk], s + 1,
                                   __ATOMIC_RELAXED, __HIP_MEMORY_SCOPE_AGENT);

            // prefetch next step's gi (hidden behind the poll)
            float nir0, niz0, nin0, nir1, niz1, nin1;
            if (s + 1 < NSTEP) {
                const float* g0 = gi + (size_t)((s + 1) * NB + m0) * G3H + j0 + jc0;
                const float* g1 = gi + (size_t)((s + 1) * NB + m1) * G3H + j0 + jc0;
                nir0 = g0[0]; niz0 = g0[512]; nin0 = g0[1024];
                nir1 = g1[0]; niz1 = g1[512]; nin1 = g1[1024];
            } else {
                nir0 = niz0 = nin0 = nir1 = niz1 = nin1 = 0.f;
            }

            // wave-0 coalesced poll of the single packed flag line
            if (wave == 0) {
                for (;;) {
                    int f = __hip_atomic_load(&flags[lane & 31], __ATOMIC_RELAXED,
                                              __HIP_MEMORY_SCOPE_AGENT);
                    if (__all(f >= s + 1)) break;
                    __builtin_amdgcn_s_sleep(1);
                }
            }
            __syncthreads();

            if (blk == 0 && tid < 8)
                __hip_atomic_store(&prog[tid << 5], s + 1,
                                   __ATOMIC_RELAXED, __HIP_MEMORY_SCOPE_AGENT);

            ir0 = nir0; iz0 = niz0; in0 = nin0;
            ir1 = nir1; iz1 = niz1; in1 = nin1;
        }

        Hfin[(size_t)m0 * HID + j0 + jc0] = hp0;
        Hfin[(size_t)m1 * HID + j0 + jc0] = hp1;

    } else {
        // ================= emit worker (double-buffered, counted vmcnt) =================
        // buffer layout: buf b at smem + b*49152: A (32768 B) then B (16384 B)
        int* myprog = prog + ((blockIdx.x & 7) << 5);
        const float NINF = -__builtin_inff();

        for (;;) {
            if (tid == 0) {
                int t = __hip_atomic_fetch_add(ticket, 1, __ATOMIC_RELAXED,
                                               __HIP_MEMORY_SCOPE_AGENT);
                tShare = t;
                if (t < NTILE) {
                    int mc = t / NT_V;
                    int need = (mc == 15) ? NSTEP : 8 * (mc + 1);
                    while (__hip_atomic_load(myprog, __ATOMIC_RELAXED,
                                             __HIP_MEMORY_SCOPE_AGENT) < need)
                        __builtin_amdgcn_s_sleep(32);
                }
            }
            __syncthreads();
            int t = tShare;
            if (t >= NTILE) break;
            int mc = t / NT_V;
            int nT = t - mc * NT_V;
            int mBase = mc * 256, nBase = nT * 128;

            f32x4 acc[4][8];
            f32x4 z = {0.f, 0.f, 0.f, 0.f};
#pragma unroll
            for (int mi = 0; mi < 4; ++mi)
#pragma unroll
                for (int ni = 0; ni < 8; ++ni) acc[mi][ni] = z;

            // prologue: stage kc=0 into buffer 0 (12 async16/wave)
            {
                __bf16* A0 = (__bf16*)smem;
                __bf16* B0 = (__bf16*)(smem + 32768);
#pragma unroll
                for (int i = 0; i < 8; ++i) {
                    int c = (wave * 8 + i) * 64 + lane;
                    int row = c >> 3, ci = c & 7, cis = ci ^ (row & 7);
                    async16(Hs + (size_t)(mBase + row) * 512 + (cis << 3),
                            A0 + (wave * 8 + i) * 512);
                }
#pragma unroll
                for (int i = 0; i < 4; ++i) {
                    int c = (wave * 4 + i) * 64 + lane;
                    int row = c >> 3, ci = c & 7, cis = ci ^ (row & 7);
                    async16(Wemb + (size_t)(nBase + row) * 512 + (cis << 3),
                            B0 + (wave * 4 + i) * 512);
                }
            }

            for (int kcIdx = 0; kcIdx < 8; ++kcIdx) {
                int cur = kcIdx & 1;
                __bf16* Ac = (__bf16*)(smem + cur * 49152);
                __bf16* Bc = (__bf16*)(smem + cur * 49152 + 32768);
                // stage next kc into the other buffer (safe: end-barrier of the
                // previous phase guarantees all reads of that buffer completed)
                if (kcIdx < 7) {
                    int kn = (kcIdx + 1) * 64;
                    __bf16* An = (__bf16*)(smem + (cur ^ 1) * 49152);
                    __bf16* Bn = (__bf16*)(smem + (cur ^ 1) * 49152 + 32768);
#pragma unroll
                    for (int i = 0; i < 8; ++i) {
                        int c = (wave * 8 + i) * 64 + lane;
                        int row = c >> 3, ci = c & 7, cis = ci ^ (row & 7);
                        async16(Hs + (size_t)(mBase + row) * 512 + kn + (cis << 3),
                                An + (wave * 8 + i) * 512);
                    }
#pragma unroll
                    for (int i = 0; i < 4; ++i) {
                        int c = (wave * 4 + i) * 64 + lane;
                        int row = c >> 3, ci = c & 7, cis = ci ^ (row & 7);
                        async16(Wemb + (size_t)(nBase + row) * 512 + kn + (cis << 3),
                                Bn + (wave * 4 + i) * 512);
                    }
                    // wait for cur's 12 loads (issued last phase); next's 12 stay in flight
                    asm volatile("s_waitcnt vmcnt(12)" ::: "memory");
                } else {
                    asm volatile("s_waitcnt vmcnt(0)" ::: "memory");
                }
                __builtin_amdgcn_s_barrier();   // all waves' cur loads landed
                __builtin_amdgcn_sched_barrier(0);

#pragma unroll
                for (int ks = 0; ks < 64; ks += 32) {
                    int L = (ks >> 3) + quad;
                    bf16x8 a4[4], b4[8];
#pragma unroll
                    for (int mi = 0; mi < 4; ++mi) {
                        int row = wave * 64 + mi * 16 + lane15;
                        a4[mi] = *(const bf16x8*)(Ac + row * 64 + ((L ^ (row & 7)) << 3));
                    }
#pragma unroll
                    for (int ni = 0; ni < 8; ++ni) {
                        int row = ni * 16 + lane15;
                        b4[ni] = *(const bf16x8*)(Bc + row * 64 + ((L ^ (row & 7)) << 3));
                    }
#pragma unroll
                    for (int mi = 0; mi < 4; ++mi)
#pragma unroll
                        for (int ni = 0; ni < 8; ++ni)
                            acc[mi][ni] = __builtin_amdgcn_mfma_f32_16x16x32_bf16(
                                a4[mi], b4[ni], acc[mi][ni], 0, 0, 0);
                }
                __builtin_amdgcn_s_barrier();   // reads of cur done before it is re-staged
            }

            float bv[8];
            bool valid[8];
#pragma unroll
            for (int ni = 0; ni < 8; ++ni) {
                int col = nBase + ni * 16 + lane15;
                valid[ni] = (col < V_SIZE);
                bv[ni] = valid[ni] ? emit_b[col] : 0.0f;
            }
#pragma unroll
            for (int mi = 0; mi < 4; ++mi) {
#pragma unroll
                for (int r = 0; r < 4; ++r) {
                    float vals[8];
                    float vmax = NINF;
#pragma unroll
                    for (int ni = 0; ni < 8; ++ni) {
                        float v = acc[mi][ni][r] + bv[ni];
                        if (!valid[ni]) v = NINF;
                        vals[ni] = v;
                        vmax = fmaxf(vmax, v);
                    }
#pragma unroll
                    for (int off = 1; off < 16; off <<= 1)
                        vmax = fmaxf(vmax, __shfl_xor(vmax, off));
                    float ssum = 0.f;
#pragma unroll
                    for (int ni = 0; ni < 8; ++ni) ssum += expf(vals[ni] - vmax);
#pragma unroll
                    for (int off = 1; off < 16; off <<= 1) ssum += __shfl_xor(ssum, off);
                    if (lane15 == 0) {
                        int m = mBase + wave * 64 + mi * 16 + quad * 4 + r;
                        partials[(size_t)m * NT_V + nT] = make_float2(vmax, ssum);
                    }
                }
            }
        }
    }
}

// ---------------- per-row log-likelihood ----------------
__global__ __launch_bounds__(128) void k_row_ll(const float2* __restrict__ partials,
                                                const __bf16* __restrict__ Hs,
                                                const __bf16* __restrict__ Wemb,
                                                const float* __restrict__ emit_b,
                                                const int* __restrict__ words,
                                                float* __restrict__ lls) {
    int s = blockIdx.x, n = blockIdx.y;
    int m = s * NB + n;
    int tid = threadIdx.x;
    int lane = tid & 63, w = tid >> 6;
    __shared__ float sm[2], ss[2], sd[2];
    const float2* prow = partials + (size_t)m * NT_V;
    float M = -__builtin_inff();
    for (int i = tid; i < NT_V; i += 128) M = fmaxf(M, prow[i].x);
#pragma unroll
    for (int off = 1; off < 64; off <<= 1) M = fmaxf(M, __shfl_xor(M, off));
    if (lane == 0) sm[w] = M;
    __syncthreads();
    M = fmaxf(sm[0], sm[1]);
    float S = 0.f;
    for (int i = tid; i < NT_V; i += 128) {
        float2 p = prow[i];
        S += p.y * expf(p.x - M);
    }
#pragma unroll
    for (int off = 1; off < 64; off <<= 1) S += __shfl_xor(S, off);
    if (lane == 0) ss[w] = S;
    __syncthreads();
    S = ss[0] + ss[1];
    int tw = words[n * TT + s + 1];
    float d = 0.f;
    const __bf16* hr = Hs + (size_t)m * HID;
    const __bf16* wr = Wemb + (size_t)tw * HID;
    for (int k = tid; k < HID; k += 128) d += (float)hr[k] * (float)wr[k];
#pragma unroll
    for (int off = 1; off < 64; off <<= 1) d += __shfl_xor(d, off);
    if (lane == 0) sd[w] = d;
    __syncthreads();
    if (tid == 0) {
        float dt = sd[0] + sd[1];
        lls[m] = dt + emit_b[tw] - (M + logf(S));
    }
}

// ---------------- final reduce ----------------
__global__ __launch_bounds__(128) void k_final(const float* __restrict__ lls,
                                               const float* __restrict__ Hfin,
                                               float* __restrict__ out) {
    int n = blockIdx.x;
    int tid = threadIdx.x;
    float s = 0.f;
    for (int i = tid; i < NSTEP; i += 128) s += lls[i * NB + n];
#pragma unroll
    for (int off = 1; off < 64; off <<= 1) s += __shfl_xor(s, off);
    __shared__ float t2[2];
    if ((tid & 63) == 0) t2[tid >> 6] = s;
    __syncthreads();
    if (tid == 0) out[n] = (t2[0] + t2[1]) / (float)NSTEP;
    for (int i = tid; i < HID; i += 128) out[NB + n * HID + i] = Hfin[(size_t)n * HID + i];
}

// ---------------- launch ----------------
extern "C" void kernel_launch(void* const* d_in, const int* in_sizes, int n_in,
                              void* d_out, int out_size, void* d_ws, size_t ws_size,
                              hipStream_t stream) {
    const int*   words   = (const int*)d_in[0];
    const float* hidden0 = (const float*)d_in[1];
    const float* embed_W = (const float*)d_in[2];
    const float* W_ih    = (const float*)d_in[3];
    const float* W_hh    = (const float*)d_in[4];
    const float* b_ih    = (const float*)d_in[5];
    const float* b_hh    = (const float*)d_in[6];
    const float* emit_W  = (const float*)d_in[7];
    const float* emit_b  = (const float*)d_in[8];
    float* out = (float*)d_out;

    char* p = (char*)d_ws;
    auto alloc = [&](size_t bytes) {
        void* r = (void*)p;
        p += (bytes + 255) & ~(size_t)255;
        return r;
    };
    __bf16* emit_Wb = (__bf16*)alloc((size_t)VPAD * 512 * 2);
    __bf16* Xb      = (__bf16*)alloc((size_t)MPAD * 512 * 2);
    __bf16* Wihb    = (__bf16*)alloc((size_t)G3H * 512 * 2);
    float*  gi      = (float*)alloc((size_t)MPAD * G3H * 4);
    __bf16* Hs      = (__bf16*)alloc((size_t)MPAD * 512 * 2);
    __bf16* Hbuf    = (__bf16*)alloc((size_t)2 * NB * HID * 2);
    float*  Hfin    = (float*)alloc((size_t)NB * HID * 4);
    float2* partials= (float2*)alloc((size_t)MPAD * NT_V * 8);
    float*  lls     = (float*)alloc((size_t)MROWS * 4);
    int*    ctrl    = (int*)alloc(2048 * 4);

    k_prep<<<PREP_GRID, 256, 0, stream>>>(words, embed_W, emit_W, W_ih, hidden0,
                                          emit_Wb, Wihb, Xb, Hs, Hbuf, ctrl);

    k_gemm_gi<<<dim3(32, 12), 256, 0, stream>>>(Xb, Wihb, b_ih, b_hh, gi);

    k_fused<<<NBLK_GRU + NWORKER, 256, 0, stream>>>(
        W_hh, gi, b_hh, hidden0, Hbuf, Hs, Hfin, emit_Wb, emit_b, partials, ctrl);

    k_row_ll<<<dim3(NSTEP, 32), 128, 0, stream>>>(partials, Hs, emit_Wb, emit_b, words, lls);
    k_final<<<32, 128, 0, stream>>>(lls, Hfin, out);
}